// Round 1
// baseline (11686.838 us; speedup 1.0000x reference)
//
#include <hip/hip_runtime.h>
#include <math.h>

// Problem constants (from reference)
constexpr int S  = 1024;
constexpr int D  = 1024;
constexpr int H  = 16;
constexpr int F  = 4096;
constexpr int NL = 3;
constexpr int C  = 5;
constexpr int HD = 64;
constexpr int B  = 8;
constexpr int MTOK = B * S;          // 8192 token rows
constexpr int QPAD = HD + 4;         // LDS pad to break bank conflicts

// ---------------------------------------------------------------- reductions
__device__ inline float block_reduce_sum_256(float v, float* red) {
  #pragma unroll
  for (int off = 32; off > 0; off >>= 1) v += __shfl_down(v, off, 64);
  int lane = threadIdx.x & 63, wid = threadIdx.x >> 6;
  if (lane == 0) red[wid] = v;
  __syncthreads();
  float t = red[0] + red[1] + red[2] + red[3];
  __syncthreads();               // allow red reuse by caller
  return t;
}

__device__ inline float gelu_f(float x) {
  return 0.5f * x * (1.0f + erff(x * 0.70710678118654752f));
}

// ---------------------------------------------------------------- embedding
__global__ __launch_bounds__(256) void embed_kernel(
    const int* __restrict__ ids, const float* __restrict__ emb,
    const float* __restrict__ pos, float* __restrict__ X) {
  int t = blockIdx.x;              // token index b*S+s
  int s = t & (S - 1);
  size_t id = (size_t)ids[t];
  const float4* e = (const float4*)(emb + id * (size_t)D);
  const float4* p = (const float4*)(pos + (size_t)s * D);
  float4* x = (float4*)(X + (size_t)t * D);
  int i = threadIdx.x;             // 256 threads * float4 == 1024 floats
  float4 a = e[i], b = p[i];
  x[i] = make_float4(a.x + b.x, a.y + b.y, a.z + b.z, a.w + b.w);
}

// ---------------------------------------------------------------- add + LN
__global__ __launch_bounds__(256) void add_ln_kernel(
    const float* __restrict__ X, const float* __restrict__ Y,
    const float* __restrict__ g, const float* __restrict__ bta,
    float* __restrict__ Out) {
  __shared__ float red[4];
  int t = blockIdx.x, i = threadIdx.x;
  const float4* xr = (const float4*)(X + (size_t)t * D);
  const float4* yr = (const float4*)(Y + (size_t)t * D);
  float4 a = xr[i], b = yr[i];
  float4 v = make_float4(a.x + b.x, a.y + b.y, a.z + b.z, a.w + b.w);
  float sum = v.x + v.y + v.z + v.w;
  sum = block_reduce_sum_256(sum, red);
  float mean = sum * (1.0f / D);
  float dx = v.x - mean, dy = v.y - mean, dz = v.z - mean, dw = v.w - mean;
  float sq = dx * dx + dy * dy + dz * dz + dw * dw;
  sq = block_reduce_sum_256(sq, red);
  float rstd = rsqrtf(sq * (1.0f / D) + 1e-5f);
  float4 gg = ((const float4*)g)[i];
  float4 bb = ((const float4*)bta)[i];
  float4 o = make_float4(dx * rstd * gg.x + bb.x, dy * rstd * gg.y + bb.y,
                         dz * rstd * gg.z + bb.z, dw * rstd * gg.w + bb.w);
  ((float4*)(Out + (size_t)t * D))[i] = o;
}

// ---------------------------------------------------------------- GEMM
// C[M,N] = A[M,K] @ W[K,N] + bias[N], optional exact-GeLU epilogue.
// 128x128 tile, BK=8, 256 threads, 8x8 accum per thread. All dims %128==0.
__global__ __launch_bounds__(256) void gemm_bias_kernel(
    const float* __restrict__ A, const float* __restrict__ W,
    const float* __restrict__ bias, float* __restrict__ Cmat,
    int M, int N, int K, int act) {
  __shared__ float As[8][128];
  __shared__ float Bs[8][128];
  int tid = threadIdx.x;
  int row0 = blockIdx.y * 128, col0 = blockIdx.x * 128;
  int tx = tid & 15, ty = tid >> 4;
  int arow = tid >> 1, acol = (tid & 1) * 4;
  int brow = tid >> 5, bcol = (tid & 31) * 4;
  const float* Aptr = A + (size_t)(row0 + arow) * K + acol;
  const float* Wptr = W + (size_t)brow * N + col0 + bcol;

  float acc[8][8];
  #pragma unroll
  for (int i = 0; i < 8; i++)
    #pragma unroll
    for (int j = 0; j < 8; j++) acc[i][j] = 0.f;

  for (int kt = 0; kt < K; kt += 8) {
    float4 av4 = *(const float4*)(Aptr + kt);
    float4 bv4 = *(const float4*)(Wptr + (size_t)kt * N);
    As[acol + 0][arow] = av4.x;
    As[acol + 1][arow] = av4.y;
    As[acol + 2][arow] = av4.z;
    As[acol + 3][arow] = av4.w;
    *(float4*)&Bs[brow][bcol] = bv4;
    __syncthreads();
    #pragma unroll
    for (int k = 0; k < 8; k++) {
      float a0[8], b0[8];
      *(float4*)&a0[0] = *(float4*)&As[k][ty * 4];
      *(float4*)&a0[4] = *(float4*)&As[k][ty * 4 + 64];
      *(float4*)&b0[0] = *(float4*)&Bs[k][tx * 4];
      *(float4*)&b0[4] = *(float4*)&Bs[k][tx * 4 + 64];
      #pragma unroll
      for (int i = 0; i < 8; i++)
        #pragma unroll
        for (int j = 0; j < 8; j++) acc[i][j] = fmaf(a0[i], b0[j], acc[i][j]);
    }
    __syncthreads();
  }

  #pragma unroll
  for (int ih = 0; ih < 2; ih++) {
    #pragma unroll
    for (int i = 0; i < 4; i++) {
      int r = row0 + ih * 64 + ty * 4 + i;
      #pragma unroll
      for (int jh = 0; jh < 2; jh++) {
        int cc = col0 + jh * 64 + tx * 4;
        float4 bb = *(const float4*)&bias[cc];
        float4 o;
        o.x = acc[ih * 4 + i][jh * 4 + 0] + bb.x;
        o.y = acc[ih * 4 + i][jh * 4 + 1] + bb.y;
        o.z = acc[ih * 4 + i][jh * 4 + 2] + bb.z;
        o.w = acc[ih * 4 + i][jh * 4 + 3] + bb.w;
        if (act) {
          o.x = gelu_f(o.x); o.y = gelu_f(o.y);
          o.z = gelu_f(o.z); o.w = gelu_f(o.w);
        }
        *(float4*)&Cmat[(size_t)r * N + cc] = o;
      }
    }
  }
}

// ---------------------------------------------------------------- attention
// Two-pass (max/sum then output) flash-style attention, fp32.
// Grid: (S/64 q-tiles, B*H). 256 threads. KV tile = 32 keys.
// Thread map: q = tid>>2 (0..63), kg/dg = tid&3.
__global__ __launch_bounds__(256) void attention_kernel(
    const float* __restrict__ Q, const float* __restrict__ Kb,
    const float* __restrict__ Vb, const int* __restrict__ amask,
    float* __restrict__ CTX) {
  __shared__ float Qs[64][QPAD];
  __shared__ float Ks[32][QPAD];
  __shared__ float Vs[32][QPAD];
  __shared__ float st[64][33];
  __shared__ float mrow[64], lrow[64];
  __shared__ float red[64][4];

  int bh = blockIdx.y;
  int b = bh >> 4, h = bh & 15;
  int q0 = blockIdx.x * 64;
  int tid = threadIdx.x;
  int q = tid >> 2, kg = tid & 3;

  // load Q tile (64 x 64)
  for (int r = tid >> 4; r < 64; r += 16) {
    int c4 = (tid & 15) * 4;
    *(float4*)&Qs[r][c4] =
        *(const float4*)&Q[((size_t)(b * S + q0 + r)) * D + h * HD + c4];
  }
  if (tid < 64) { mrow[tid] = -1e30f; lrow[tid] = 0.f; }
  __syncthreads();

  // ---------------- pass 1: running max + denom
  for (int k0 = 0; k0 < S; k0 += 32) {
    for (int r = tid >> 4; r < 32; r += 16) {
      int c4 = (tid & 15) * 4;
      *(float4*)&Ks[r][c4] =
          *(const float4*)&Kb[((size_t)(b * S + k0 + r)) * D + h * HD + c4];
    }
    __syncthreads();                                   // (A)

    float sv[8];
    #pragma unroll
    for (int i = 0; i < 8; i++) sv[i] = 0.f;
    #pragma unroll
    for (int d0 = 0; d0 < HD; d0 += 16) {
      float qreg[16];
      #pragma unroll
      for (int j = 0; j < 16; j += 4)
        *(float4*)&qreg[j] = *(const float4*)&Qs[q][d0 + j];
      #pragma unroll
      for (int i = 0; i < 8; i++) {
        int kk = kg * 8 + i;
        #pragma unroll
        for (int j = 0; j < 16; j += 4) {
          float4 kv = *(const float4*)&Ks[kk][d0 + j];
          sv[i] = fmaf(qreg[j + 0], kv.x, sv[i]);
          sv[i] = fmaf(qreg[j + 1], kv.y, sv[i]);
          sv[i] = fmaf(qreg[j + 2], kv.z, sv[i]);
          sv[i] = fmaf(qreg[j + 3], kv.w, sv[i]);
        }
      }
    }
    float pmax = -1e30f;
    #pragma unroll
    for (int i = 0; i < 8; i++) {
      int kglob = k0 + kg * 8 + i;
      float s = sv[i] * 0.125f;
      if (amask[b * S + kglob] == 0) s = -1e9f;
      sv[i] = s;
      pmax = fmaxf(pmax, s);
    }
    red[q][kg] = pmax;
    __syncthreads();                                   // (B)
    float mnew = fmaxf(fmaxf(red[q][0], red[q][1]),
                       fmaxf(red[q][2], red[q][3]));
    mnew = fmaxf(mnew, mrow[q]);
    float psum = 0.f;
    #pragma unroll
    for (int i = 0; i < 8; i++) psum += __expf(sv[i] - mnew);
    __syncthreads();                                   // (C) red reuse
    red[q][kg] = psum;
    __syncthreads();                                   // (D)
    if (kg == 0) {
      float mold = mrow[q];
      lrow[q] = lrow[q] * __expf(mold - mnew) +
                red[q][0] + red[q][1] + red[q][2] + red[q][3];
      mrow[q] = mnew;
    }
    __syncthreads();
  }

  float mq = mrow[q];
  float linv = 1.0f / lrow[q];
  float out[16];
  #pragma unroll
  for (int j = 0; j < 16; j++) out[j] = 0.f;

  // ---------------- pass 2: recompute scores, accumulate P @ V
  for (int k0 = 0; k0 < S; k0 += 32) {
    for (int r = tid >> 4; r < 32; r += 16) {
      int c4 = (tid & 15) * 4;
      size_t base = ((size_t)(b * S + k0 + r)) * D + h * HD + c4;
      *(float4*)&Ks[r][c4] = *(const float4*)&Kb[base];
      *(float4*)&Vs[r][c4] = *(const float4*)&Vb[base];
    }
    __syncthreads();                                   // (A)

    float sv[8];
    #pragma unroll
    for (int i = 0; i < 8; i++) sv[i] = 0.f;
    #pragma unroll
    for (int d0 = 0; d0 < HD; d0 += 16) {
      float qreg[16];
      #pragma unroll
      for (int j = 0; j < 16; j += 4)
        *(float4*)&qreg[j] = *(const float4*)&Qs[q][d0 + j];
      #pragma unroll
      for (int i = 0; i < 8; i++) {
        int kk = kg * 8 + i;
        #pragma unroll
        for (int j = 0; j < 16; j += 4) {
          float4 kv = *(const float4*)&Ks[kk][d0 + j];
          sv[i] = fmaf(qreg[j + 0], kv.x, sv[i]);
          sv[i] = fmaf(qreg[j + 1], kv.y, sv[i]);
          sv[i] = fmaf(qreg[j + 2], kv.z, sv[i]);
          sv[i] = fmaf(qreg[j + 3], kv.w, sv[i]);
        }
      }
    }
    #pragma unroll
    for (int i = 0; i < 8; i++) {
      int kglob = k0 + kg * 8 + i;
      float s = sv[i] * 0.125f;
      if (amask[b * S + kglob] == 0) s = -1e9f;
      st[q][kg * 8 + i] = __expf(s - mq) * linv;
    }
    __syncthreads();                                   // (B)

    int dg = tid & 3;
    #pragma unroll 4
    for (int kk = 0; kk < 32; kk++) {
      float p = st[q][kk];
      #pragma unroll
      for (int j = 0; j < 16; j += 4) {
        float4 v = *(const float4*)&Vs[kk][dg * 16 + j];
        out[j + 0] = fmaf(p, v.x, out[j + 0]);
        out[j + 1] = fmaf(p, v.y, out[j + 1]);
        out[j + 2] = fmaf(p, v.z, out[j + 2]);
        out[j + 3] = fmaf(p, v.w, out[j + 3]);
      }
    }
    __syncthreads();                                   // (C)
  }

  int dg = tid & 3;
  size_t obase = ((size_t)(b * S + q0 + q)) * D + h * HD + dg * 16;
  #pragma unroll
  for (int j = 0; j < 16; j += 4)
    *(float4*)&CTX[obase + j] = *(float4*)&out[j];
}

// ---------------------------------------------------------------- classifier
__global__ __launch_bounds__(256) void classifier_kernel(
    const float* __restrict__ X, const float* __restrict__ g,
    const float* __restrict__ bta, const float* __restrict__ Wc,
    const float* __restrict__ bc, float* __restrict__ out) {
  __shared__ float red[4];
  __shared__ float xn[D];
  int b = blockIdx.x, i = threadIdx.x;
  const float4* xr = (const float4*)(X + (size_t)b * S * D);  // token 0
  float4 v = xr[i];
  float sum = v.x + v.y + v.z + v.w;
  sum = block_reduce_sum_256(sum, red);
  float mean = sum * (1.0f / D);
  float dx = v.x - mean, dy = v.y - mean, dz = v.z - mean, dw = v.w - mean;
  float sq = dx * dx + dy * dy + dz * dz + dw * dw;
  sq = block_reduce_sum_256(sq, red);
  float rstd = rsqrtf(sq * (1.0f / D) + 1e-5f);
  float4 gg = ((const float4*)g)[i];
  float4 bb = ((const float4*)bta)[i];
  float4 o = make_float4(dx * rstd * gg.x + bb.x, dy * rstd * gg.y + bb.y,
                         dz * rstd * gg.z + bb.z, dw * rstd * gg.w + bb.w);
  *(float4*)&xn[i * 4] = o;
  __syncthreads();
  for (int c = 0; c < C; c++) {
    float p = 0.f;
    for (int d = i; d < D; d += 256) p += xn[d] * Wc[(size_t)d * C + c];
    p = block_reduce_sum_256(p, red);
    if (i == 0) out[b * C + c] = p + bc[c];
  }
}

// ---------------------------------------------------------------- launch
extern "C" void kernel_launch(void* const* d_in, const int* in_sizes, int n_in,
                              void* d_out, int out_size, void* d_ws,
                              size_t ws_size, hipStream_t stream) {
  const int*   ids   = (const int*)d_in[0];
  const int*   amask = (const int*)d_in[1];
  const float* emb   = (const float*)d_in[2];
  const float* pos   = (const float*)d_in[3];
  const float* Wq    = (const float*)d_in[4];
  const float* bq    = (const float*)d_in[5];
  const float* Wk    = (const float*)d_in[6];
  const float* bk    = (const float*)d_in[7];
  const float* Wv    = (const float*)d_in[8];
  const float* bv    = (const float*)d_in[9];
  const float* Wo    = (const float*)d_in[10];
  const float* bo    = (const float*)d_in[11];
  const float* ln1g  = (const float*)d_in[12];
  const float* ln1b  = (const float*)d_in[13];
  const float* ln2g  = (const float*)d_in[14];
  const float* ln2b  = (const float*)d_in[15];
  const float* W1    = (const float*)d_in[16];
  const float* b1    = (const float*)d_in[17];
  const float* W2    = (const float*)d_in[18];
  const float* b2    = (const float*)d_in[19];
  const float* cg    = (const float*)d_in[20];
  const float* cb    = (const float*)d_in[21];
  const float* Wc    = (const float*)d_in[22];
  const float* bc    = (const float*)d_in[23];
  float* logits = (float*)d_out;

  // Workspace layout (peak 48M floats = 192 MB):
  //   X   : 8M  activations (residual stream)
  //   Y   : 8M  temp (attn out pre-proj / FF out)
  //   BIG : 32M time-shared: {Q,K,V,O2} during attention, FF hidden after.
  float* ws = (float*)d_ws;
  const size_t NT = (size_t)MTOK * D;  // 8M floats
  float* X   = ws;
  float* Y   = X + NT;
  float* BIG = Y + NT;
  float* Qb = BIG, *Kb = BIG + NT, *Vb = BIG + 2 * NT, *O2 = BIG + 3 * NT;
  float* Hh = BIG;  // 32M floats (8192 x 4096), aliases Q/K/V/O2 (dead then)

  embed_kernel<<<MTOK, 256, 0, stream>>>(ids, emb, pos, X);

  dim3 gD(D / 128, MTOK / 128);   // N=1024 GEMMs
  dim3 gF(F / 128, MTOK / 128);   // N=4096 GEMM
  for (int l = 0; l < NL; l++) {
    gemm_bias_kernel<<<gD, 256, 0, stream>>>(
        X, Wq + (size_t)l * D * D, bq + l * D, Qb, MTOK, D, D, 0);
    gemm_bias_kernel<<<gD, 256, 0, stream>>>(
        X, Wk + (size_t)l * D * D, bk + l * D, Kb, MTOK, D, D, 0);
    gemm_bias_kernel<<<gD, 256, 0, stream>>>(
        X, Wv + (size_t)l * D * D, bv + l * D, Vb, MTOK, D, D, 0);
    attention_kernel<<<dim3(S / 64, B * H), 256, 0, stream>>>(
        Qb, Kb, Vb, amask, Y);
    gemm_bias_kernel<<<gD, 256, 0, stream>>>(
        Y, Wo + (size_t)l * D * D, bo + l * D, O2, MTOK, D, D, 0);
    add_ln_kernel<<<MTOK, 256, 0, stream>>>(
        X, O2, ln1g + l * D, ln1b + l * D, X);
    gemm_bias_kernel<<<gF, 256, 0, stream>>>(
        X, W1 + (size_t)l * D * F, b1 + l * F, Hh, MTOK, F, D, 1);
    gemm_bias_kernel<<<gD, 256, 0, stream>>>(
        Hh, W2 + (size_t)l * F * D, b2 + l * D, Y, MTOK, D, F, 0);
    add_ln_kernel<<<MTOK, 256, 0, stream>>>(
        X, Y, ln2g + l * D, ln2b + l * D, X);
  }
  classifier_kernel<<<B, 256, 0, stream>>>(X, cg, cb, Wc, bc, logits);
}

// Round 3
// 4462.317 us; speedup vs baseline: 2.6190x; 2.6190x over previous
//
#include <hip/hip_runtime.h>
#include <math.h>

// Problem constants
constexpr int S  = 1024;
constexpr int D  = 1024;
constexpr int H  = 16;
constexpr int F  = 4096;
constexpr int NL = 3;
constexpr int C  = 5;
constexpr int HD = 64;
constexpr int B  = 8;
constexpr int MTOK = B * S;          // 8192 token rows
constexpr int QPAD = HD + 4;

typedef unsigned short u16;
typedef __attribute__((ext_vector_type(4))) float f32x4;
typedef __attribute__((ext_vector_type(4))) int   i32x4;

// ---- bf16 <-> f32 helpers (RNE, no header dependence) ----------------------
__device__ inline u16 f2b(float x) {
  unsigned u = __float_as_uint(x);
  unsigned r = (u + 0x7fffu + ((u >> 16) & 1u)) >> 16;
  return (u16)r;
}
__device__ inline float b2f(u16 b) {
  return __uint_as_float(((unsigned)b) << 16);
}
__device__ inline float4 ld_bf4(const u16* p) {
  ushort4 u = *(const ushort4*)p;
  return make_float4(b2f(u.x), b2f(u.y), b2f(u.z), b2f(u.w));
}

// ---- async global->LDS, 16B per lane ---------------------------------------
#define GLD16(gptr, lptr)                                                  \
  __builtin_amdgcn_global_load_lds(                                        \
      (const __attribute__((address_space(1))) void*)(gptr),               \
      (__attribute__((address_space(3))) void*)(lptr), 16, 0, 0)

// ---- MFMA via inline asm ----------------------------------------------------
__device__ inline void mfma16(f32x4& acc, i32x4 a, i32x4 b) {
  asm("v_mfma_f32_16x16x32_bf16 %0, %1, %2, %0" : "+v"(acc) : "v"(a), "v"(b));
}

// ---------------------------------------------------------------- reductions
__device__ inline float block_reduce_sum_256(float v, float* red) {
  #pragma unroll
  for (int off = 32; off > 0; off >>= 1) v += __shfl_down(v, off, 64);
  int lane = threadIdx.x & 63, wid = threadIdx.x >> 6;
  if (lane == 0) red[wid] = v;
  __syncthreads();
  float t = red[0] + red[1] + red[2] + red[3];
  __syncthreads();
  return t;
}

__device__ inline float gelu_f(float x) {
  return 0.5f * x * (1.0f + erff(x * 0.70710678118654752f));
}

// ---------------------------------------------------------------- embedding
__global__ __launch_bounds__(256) void embed_kernel(
    const int* __restrict__ ids, const float* __restrict__ emb,
    const float* __restrict__ pos, float* __restrict__ X,
    u16* __restrict__ Xb) {
  int t = blockIdx.x;
  int s = t & (S - 1);
  size_t id = (size_t)ids[t];
  const float4* e = (const float4*)(emb + id * (size_t)D);
  const float4* p = (const float4*)(pos + (size_t)s * D);
  int i = threadIdx.x;
  float4 a = e[i], b = p[i];
  float4 v = make_float4(a.x + b.x, a.y + b.y, a.z + b.z, a.w + b.w);
  ((float4*)(X + (size_t)t * D))[i] = v;
  ushort4 o = {f2b(v.x), f2b(v.y), f2b(v.z), f2b(v.w)};
  *(ushort4*)&Xb[(size_t)t * D + i * 4] = o;
}

// ---------------------------------------------------------------- add + LN
__global__ __launch_bounds__(256) void add_ln_kernel(
    const float* __restrict__ X, const float* __restrict__ Y,
    const float* __restrict__ g, const float* __restrict__ bta,
    float* __restrict__ Out, u16* __restrict__ Outb) {
  __shared__ float red[4];
  int t = blockIdx.x, i = threadIdx.x;
  const float4* xr = (const float4*)(X + (size_t)t * D);
  const float4* yr = (const float4*)(Y + (size_t)t * D);
  float4 a = xr[i], b = yr[i];
  float4 v = make_float4(a.x + b.x, a.y + b.y, a.z + b.z, a.w + b.w);
  float sum = v.x + v.y + v.z + v.w;
  sum = block_reduce_sum_256(sum, red);
  float mean = sum * (1.0f / D);
  float dx = v.x - mean, dy = v.y - mean, dz = v.z - mean, dw = v.w - mean;
  float sq = dx * dx + dy * dy + dz * dz + dw * dw;
  sq = block_reduce_sum_256(sq, red);
  float rstd = rsqrtf(sq * (1.0f / D) + 1e-5f);
  float4 gg = ((const float4*)g)[i];
  float4 bb = ((const float4*)bta)[i];
  float4 o = make_float4(dx * rstd * gg.x + bb.x, dy * rstd * gg.y + bb.y,
                         dz * rstd * gg.z + bb.z, dw * rstd * gg.w + bb.w);
  ((float4*)(Out + (size_t)t * D))[i] = o;
  ushort4 ob = {f2b(o.x), f2b(o.y), f2b(o.z), f2b(o.w)};
  *(ushort4*)&Outb[(size_t)t * D + i * 4] = ob;
}

// ---------------------------------------------------------------- transpose+cast
// W [K,N] fp32 -> WT [N,K] bf16.  Grid (N/32, K/32), 256 threads.
__global__ __launch_bounds__(256) void transpose_cast_kernel(
    const float* __restrict__ W, u16* __restrict__ WT, int K, int N) {
  __shared__ float t[32][33];
  int r = threadIdx.x >> 3, c4 = (threadIdx.x & 7) * 4;
  *(float4*)&t[r][c4] =
      *(const float4*)&W[(size_t)(blockIdx.y * 32 + r) * N + blockIdx.x * 32 + c4];
  __syncthreads();
  int n = blockIdx.x * 32 + r;
  int k = blockIdx.y * 32 + c4;
  ushort4 o = {f2b(t[c4 + 0][r]), f2b(t[c4 + 1][r]),
               f2b(t[c4 + 2][r]), f2b(t[c4 + 3][r])};
  *(ushort4*)&WT[(size_t)n * K + k] = o;
}

// ---------------------------------------------------------------- MFMA GEMM
// C[M,N] = A[M,K](bf16) @ BT[N,K](bf16)^T + bias, m97-structure:
// 128x128 tile, BK=32, 256 threads (4 waves 2x2), 4x4 16x16x32 frags/wave.
template <int OUTBF16, int ACT>
__global__ __launch_bounds__(256) void gemm_mfma(
    const u16* __restrict__ A, const u16* __restrict__ BT,
    const float* __restrict__ bias, void* __restrict__ Cout,
    int M, int N, int K) {
  __shared__ u16 As[128][32];   // 8 KB
  __shared__ u16 Bs[128][32];   // 8 KB
  int tid = threadIdx.x;
  int row0 = blockIdx.y * 128, col0 = blockIdx.x * 128;
  int wid = tid >> 6, lane = tid & 63;
  int wr = (wid >> 1) * 64, wc = (wid & 1) * 64;
  int fr = lane & 15, fq = lane >> 4;

  f32x4 acc[4][4];
  #pragma unroll
  for (int m = 0; m < 4; m++)
    #pragma unroll
    for (int n = 0; n < 4; n++) acc[m][n] = (f32x4)(0.0f);

  for (int kt = 0; kt < K; kt += 32) {
    #pragma unroll
    for (int i = 0; i < 2; i++) {
      int f = i * 256 + tid;
      int r = f >> 2, ks = (f & 3) * 8;
      GLD16(A + (size_t)(row0 + r) * K + kt + ks, &As[r][ks]);
    }
    #pragma unroll
    for (int i = 0; i < 2; i++) {
      int f = i * 256 + tid;
      int r = f >> 2, ks = (f & 3) * 8;
      GLD16(BT + (size_t)(col0 + r) * K + kt + ks, &Bs[r][ks]);
    }
    __syncthreads();
    i32x4 av[4], bv[4];
    #pragma unroll
    for (int m = 0; m < 4; m++)
      av[m] = *(const i32x4*)&As[wr + m * 16 + fr][fq * 8];
    #pragma unroll
    for (int n = 0; n < 4; n++)
      bv[n] = *(const i32x4*)&Bs[wc + n * 16 + fr][fq * 8];
    #pragma unroll
    for (int m = 0; m < 4; m++)
      #pragma unroll
      for (int n = 0; n < 4; n++) mfma16(acc[m][n], av[m], bv[n]);
    __syncthreads();
  }

  // epilogue: C row = row0+wr+m*16+fq*4+j, col = col0+wc+n*16+fr (m89/m91 layout)
  float* Cf = (float*)Cout;
  u16*   Cb = (u16*)Cout;
  #pragma unroll
  for (int n = 0; n < 4; n++) {
    int c = col0 + wc + n * 16 + fr;
    float bvl = bias[c];
    #pragma unroll
    for (int m = 0; m < 4; m++) {
      #pragma unroll
      for (int j = 0; j < 4; j++) {
        int r = row0 + wr + m * 16 + fq * 4 + j;
        float v = acc[m][n][j] + bvl;
        if (ACT) v = gelu_f(v);
        if (OUTBF16) Cb[(size_t)r * N + c] = f2b(v);
        else         Cf[(size_t)r * N + c] = v;
      }
    }
  }
}

// ---------------------------------------------------------------- attention
// fp32 internals; bf16 I/O. Key assignment kk = i*4+kg so the 4 K-rows read
// concurrently are consecutive (banks 0/4/8/12 apart) instead of 8 rows
// apart (8*QPAD==544 ≡ 0 mod 32 -> was a 4-way bank conflict).
__global__ __launch_bounds__(256) void attention_kernel(
    const u16* __restrict__ Q, const u16* __restrict__ Kb,
    const u16* __restrict__ Vb, const int* __restrict__ amask,
    u16* __restrict__ CTX) {
  __shared__ float Qs[64][QPAD];
  __shared__ float Ks[32][QPAD];
  __shared__ float Vs[32][QPAD];
  __shared__ float st[64][33];
  __shared__ float mrow[64], lrow[64];
  __shared__ float red[64][4];

  int bh = blockIdx.y;
  int b = bh >> 4, h = bh & 15;
  int q0 = blockIdx.x * 64;
  int tid = threadIdx.x;
  int q = tid >> 2, kg = tid & 3;

  for (int r = tid >> 4; r < 64; r += 16) {
    int c4 = (tid & 15) * 4;
    *(float4*)&Qs[r][c4] =
        ld_bf4(&Q[((size_t)(b * S + q0 + r)) * D + h * HD + c4]);
  }
  if (tid < 64) { mrow[tid] = -1e30f; lrow[tid] = 0.f; }
  __syncthreads();

  // pass 1: running max + denom
  for (int k0 = 0; k0 < S; k0 += 32) {
    for (int r = tid >> 4; r < 32; r += 16) {
      int c4 = (tid & 15) * 4;
      *(float4*)&Ks[r][c4] =
          ld_bf4(&Kb[((size_t)(b * S + k0 + r)) * D + h * HD + c4]);
    }
    __syncthreads();

    float sv[8];
    #pragma unroll
    for (int i = 0; i < 8; i++) sv[i] = 0.f;
    #pragma unroll
    for (int d0 = 0; d0 < HD; d0 += 16) {
      float qreg[16];
      #pragma unroll
      for (int j = 0; j < 16; j += 4)
        *(float4*)&qreg[j] = *(float4*)&Qs[q][d0 + j];
      #pragma unroll
      for (int i = 0; i < 8; i++) {
        int kk = i * 4 + kg;
        #pragma unroll
        for (int j = 0; j < 16; j += 4) {
          float4 kv = *(float4*)&Ks[kk][d0 + j];
          sv[i] = fmaf(qreg[j + 0], kv.x, sv[i]);
          sv[i] = fmaf(qreg[j + 1], kv.y, sv[i]);
          sv[i] = fmaf(qreg[j + 2], kv.z, sv[i]);
          sv[i] = fmaf(qreg[j + 3], kv.w, sv[i]);
        }
      }
    }
    float pmax = -1e30f;
    #pragma unroll
    for (int i = 0; i < 8; i++) {
      int kglob = k0 + i * 4 + kg;
      float s = sv[i] * 0.125f;
      if (amask[b * S + kglob] == 0) s = -1e9f;
      sv[i] = s;
      pmax = fmaxf(pmax, s);
    }
    red[q][kg] = pmax;
    __syncthreads();
    float mnew = fmaxf(fmaxf(red[q][0], red[q][1]),
                       fmaxf(red[q][2], red[q][3]));
    mnew = fmaxf(mnew, mrow[q]);
    float psum = 0.f;
    #pragma unroll
    for (int i = 0; i < 8; i++) psum += __expf(sv[i] - mnew);
    __syncthreads();
    red[q][kg] = psum;
    __syncthreads();
    if (kg == 0) {
      float mold = mrow[q];
      lrow[q] = lrow[q] * __expf(mold - mnew) +
                red[q][0] + red[q][1] + red[q][2] + red[q][3];
      mrow[q] = mnew;
    }
    __syncthreads();
  }

  float mq = mrow[q];
  float linv = 1.0f / lrow[q];
  float out[16];
  #pragma unroll
  for (int j = 0; j < 16; j++) out[j] = 0.f;

  // pass 2: recompute scores, accumulate P @ V
  for (int k0 = 0; k0 < S; k0 += 32) {
    for (int r = tid >> 4; r < 32; r += 16) {
      int c4 = (tid & 15) * 4;
      size_t base = ((size_t)(b * S + k0 + r)) * D + h * HD + c4;
      *(float4*)&Ks[r][c4] = ld_bf4(&Kb[base]);
      *(float4*)&Vs[r][c4] = ld_bf4(&Vb[base]);
    }
    __syncthreads();

    float sv[8];
    #pragma unroll
    for (int i = 0; i < 8; i++) sv[i] = 0.f;
    #pragma unroll
    for (int d0 = 0; d0 < HD; d0 += 16) {
      float qreg[16];
      #pragma unroll
      for (int j = 0; j < 16; j += 4)
        *(float4*)&qreg[j] = *(float4*)&Qs[q][d0 + j];
      #pragma unroll
      for (int i = 0; i < 8; i++) {
        int kk = i * 4 + kg;
        #pragma unroll
        for (int j = 0; j < 16; j += 4) {
          float4 kv = *(float4*)&Ks[kk][d0 + j];
          sv[i] = fmaf(qreg[j + 0], kv.x, sv[i]);
          sv[i] = fmaf(qreg[j + 1], kv.y, sv[i]);
          sv[i] = fmaf(qreg[j + 2], kv.z, sv[i]);
          sv[i] = fmaf(qreg[j + 3], kv.w, sv[i]);
        }
      }
    }
    #pragma unroll
    for (int i = 0; i < 8; i++) {
      int kglob = k0 + i * 4 + kg;
      float s = sv[i] * 0.125f;
      if (amask[b * S + kglob] == 0) s = -1e9f;
      st[q][i * 4 + kg] = __expf(s - mq) * linv;
    }
    __syncthreads();

    int dg = tid & 3;
    #pragma unroll 4
    for (int kk = 0; kk < 32; kk++) {
      float p = st[q][kk];
      #pragma unroll
      for (int j = 0; j < 16; j += 4) {
        float4 v = *(float4*)&Vs[kk][dg * 16 + j];
        out[j + 0] = fmaf(p, v.x, out[j + 0]);
        out[j + 1] = fmaf(p, v.y, out[j + 1]);
        out[j + 2] = fmaf(p, v.z, out[j + 2]);
        out[j + 3] = fmaf(p, v.w, out[j + 3]);
      }
    }
    __syncthreads();
  }

  int dg = tid & 3;
  size_t obase = ((size_t)(b * S + q0 + q)) * D + h * HD + dg * 16;
  #pragma unroll
  for (int j = 0; j < 16; j += 4) {
    ushort4 o = {f2b(out[j]), f2b(out[j + 1]), f2b(out[j + 2]), f2b(out[j + 3])};
    *(ushort4*)&CTX[obase + j] = o;
  }
}

// ---------------------------------------------------------------- classifier
__global__ __launch_bounds__(256) void classifier_kernel(
    const float* __restrict__ X, const float* __restrict__ g,
    const float* __restrict__ bta, const float* __restrict__ Wc,
    const float* __restrict__ bc, float* __restrict__ out) {
  __shared__ float red[4];
  __shared__ float xn[D];
  int b = blockIdx.x, i = threadIdx.x;
  const float4* xr = (const float4*)(X + (size_t)b * S * D);
  float4 v = xr[i];
  float sum = v.x + v.y + v.z + v.w;
  sum = block_reduce_sum_256(sum, red);
  float mean = sum * (1.0f / D);
  float dx = v.x - mean, dy = v.y - mean, dz = v.z - mean, dw = v.w - mean;
  float sq = dx * dx + dy * dy + dz * dz + dw * dw;
  sq = block_reduce_sum_256(sq, red);
  float rstd = rsqrtf(sq * (1.0f / D) + 1e-5f);
  float4 gg = ((const float4*)g)[i];
  float4 bb = ((const float4*)bta)[i];
  float4 o = make_float4(dx * rstd * gg.x + bb.x, dy * rstd * gg.y + bb.y,
                         dz * rstd * gg.z + bb.z, dw * rstd * gg.w + bb.w);
  *(float4*)&xn[i * 4] = o;
  __syncthreads();
  for (int c = 0; c < C; c++) {
    float p = 0.f;
    for (int d = i; d < D; d += 256) p += xn[d] * Wc[(size_t)d * C + c];
    p = block_reduce_sum_256(p, red);
    if (i == 0) out[b * C + c] = p + bc[c];
  }
}

// ---------------------------------------------------------------- launch
extern "C" void kernel_launch(void* const* d_in, const int* in_sizes, int n_in,
                              void* d_out, int out_size, void* d_ws,
                              size_t ws_size, hipStream_t stream) {
  const int*   ids   = (const int*)d_in[0];
  const int*   amask = (const int*)d_in[1];
  const float* emb   = (const float*)d_in[2];
  const float* pos   = (const float*)d_in[3];
  const float* Wq    = (const float*)d_in[4];
  const float* bq    = (const float*)d_in[5];
  const float* Wk    = (const float*)d_in[6];
  const float* bk    = (const float*)d_in[7];
  const float* Wv    = (const float*)d_in[8];
  const float* bv    = (const float*)d_in[9];
  const float* Wo    = (const float*)d_in[10];
  const float* bo    = (const float*)d_in[11];
  const float* ln1g  = (const float*)d_in[12];
  const float* ln1b  = (const float*)d_in[13];
  const float* ln2g  = (const float*)d_in[14];
  const float* ln2b  = (const float*)d_in[15];
  const float* W1    = (const float*)d_in[16];
  const float* b1    = (const float*)d_in[17];
  const float* W2    = (const float*)d_in[18];
  const float* b2    = (const float*)d_in[19];
  const float* cg    = (const float*)d_in[20];
  const float* cb    = (const float*)d_in[21];
  const float* Wc    = (const float*)d_in[22];
  const float* bc    = (const float*)d_in[23];
  float* logits = (float*)d_out;

  // Workspace layout (bytes), total 168 MB:
  //   [0,32M)    X   fp32 residual
  //   [32,64M)   Y   fp32 temp
  //   [64,80M)   Xb  bf16 residual
  //   [80,144M)  BIG: Qb/Kb/Vb/CTXb bf16 (attention) | Hh bf16 (FF hidden)
  //   [144,168M) per-layer transposed bf16 weights
  const size_t MB = 1u << 20;
  char* w = (char*)d_ws;
  float* X   = (float*)(w + 0 * MB);
  float* Y   = (float*)(w + 32 * MB);
  u16* Xb    = (u16*)(w + 64 * MB);
  u16* Qb    = (u16*)(w + 80 * MB);
  u16* Kbuf  = (u16*)(w + 96 * MB);
  u16* Vbuf  = (u16*)(w + 112 * MB);
  u16* CTXb  = (u16*)(w + 128 * MB);
  u16* Hh    = (u16*)(w + 80 * MB);    // aliases Qb..CTXb (dead by then)
  u16* WTq   = (u16*)(w + 144 * MB);
  u16* WTk   = (u16*)(w + 146 * MB);
  u16* WTv   = (u16*)(w + 148 * MB);
  u16* WTo   = (u16*)(w + 150 * MB);
  u16* WT1   = (u16*)(w + 152 * MB);
  u16* WT2   = (u16*)(w + 160 * MB);

  embed_kernel<<<MTOK, 256, 0, stream>>>(ids, emb, pos, X, Xb);

  dim3 tDD(D / 32, D / 32);
  dim3 tFD(F / 32, D / 32);   // W1 [D,F]
  dim3 tDF(D / 32, F / 32);   // W2 [F,D]
  dim3 gD(D / 128, MTOK / 128);
  dim3 gF(F / 128, MTOK / 128);

  for (int l = 0; l < NL; l++) {
    transpose_cast_kernel<<<tDD, 256, 0, stream>>>(Wq + (size_t)l * D * D, WTq, D, D);
    transpose_cast_kernel<<<tDD, 256, 0, stream>>>(Wk + (size_t)l * D * D, WTk, D, D);
    transpose_cast_kernel<<<tDD, 256, 0, stream>>>(Wv + (size_t)l * D * D, WTv, D, D);
    transpose_cast_kernel<<<tDD, 256, 0, stream>>>(Wo + (size_t)l * D * D, WTo, D, D);
    transpose_cast_kernel<<<tFD, 256, 0, stream>>>(W1 + (size_t)l * D * F, WT1, D, F);
    transpose_cast_kernel<<<tDF, 256, 0, stream>>>(W2 + (size_t)l * F * D, WT2, F, D);

    gemm_mfma<1, 0><<<gD, 256, 0, stream>>>(Xb, WTq, bq + l * D, Qb,   MTOK, D, D);
    gemm_mfma<1, 0><<<gD, 256, 0, stream>>>(Xb, WTk, bk + l * D, Kbuf, MTOK, D, D);
    gemm_mfma<1, 0><<<gD, 256, 0, stream>>>(Xb, WTv, bv + l * D, Vbuf, MTOK, D, D);

    attention_kernel<<<dim3(S / 64, B * H), 256, 0, stream>>>(
        Qb, Kbuf, Vbuf, amask, CTXb);

    gemm_mfma<0, 0><<<gD, 256, 0, stream>>>(CTXb, WTo, bo + l * D, Y, MTOK, D, D);
    add_ln_kernel<<<MTOK, 256, 0, stream>>>(X, Y, ln1g + l * D, ln1b + l * D, X, Xb);

    gemm_mfma<1, 1><<<gF, 256, 0, stream>>>(Xb, WT1, b1 + l * F, Hh, MTOK, F, D);
    gemm_mfma<0, 0><<<gD, 256, 0, stream>>>(Hh, WT2, b2 + l * D, Y, MTOK, D, F);
    add_ln_kernel<<<MTOK, 256, 0, stream>>>(X, Y, ln2g + l * D, ln2b + l * D, X, Xb);
  }
  classifier_kernel<<<B, 256, 0, stream>>>(X, cg, cb, Wc, bc, logits);
}

// Round 4
// 1720.949 us; speedup vs baseline: 6.7909x; 2.5929x over previous
//
#include <hip/hip_runtime.h>
#include <math.h>

// Problem constants
constexpr int S  = 1024;
constexpr int D  = 1024;
constexpr int H  = 16;
constexpr int F  = 4096;
constexpr int NL = 3;
constexpr int C  = 5;
constexpr int HD = 64;
constexpr int B  = 8;
constexpr int MTOK = B * S;          // 8192 token rows

typedef unsigned short u16;
typedef __attribute__((ext_vector_type(4))) float f32x4;
typedef __attribute__((ext_vector_type(4))) int   i32x4;

// ---- bf16 <-> f32 helpers (RNE) --------------------------------------------
__device__ inline u16 f2b(float x) {
  unsigned u = __float_as_uint(x);
  unsigned r = (u + 0x7fffu + ((u >> 16) & 1u)) >> 16;
  return (u16)r;
}
__device__ inline float b2f(u16 b) {
  return __uint_as_float(((unsigned)b) << 16);
}

// ---- async global->LDS, 16B per lane ---------------------------------------
#define GLD16(gptr, lptr)                                                  \
  __builtin_amdgcn_global_load_lds(                                        \
      (const __attribute__((address_space(1))) void*)(gptr),               \
      (__attribute__((address_space(3))) void*)(lptr), 16, 0, 0)

// ---- MFMA -------------------------------------------------------------------
__device__ inline void mfma16(f32x4& acc, i32x4 a, i32x4 b) {
  asm("v_mfma_f32_16x16x32_bf16 %0, %1, %2, %0" : "+v"(acc) : "v"(a), "v"(b));
}

// ---------------------------------------------------------------- reductions
__device__ inline float block_reduce_sum_256(float v, float* red) {
  #pragma unroll
  for (int off = 32; off > 0; off >>= 1) v += __shfl_down(v, off, 64);
  int lane = threadIdx.x & 63, wid = threadIdx.x >> 6;
  if (lane == 0) red[wid] = v;
  __syncthreads();
  float t = red[0] + red[1] + red[2] + red[3];
  __syncthreads();
  return t;
}

__device__ inline float gelu_f(float x) {
  return 0.5f * x * (1.0f + erff(x * 0.70710678118654752f));
}

// ---------------------------------------------------------------- embedding
__global__ __launch_bounds__(256) void embed_kernel(
    const int* __restrict__ ids, const float* __restrict__ emb,
    const float* __restrict__ pos, float* __restrict__ X,
    u16* __restrict__ Xb) {
  int t = blockIdx.x;
  int s = t & (S - 1);
  size_t id = (size_t)ids[t];
  const float4* e = (const float4*)(emb + id * (size_t)D);
  const float4* p = (const float4*)(pos + (size_t)s * D);
  int i = threadIdx.x;
  float4 a = e[i], b = p[i];
  float4 v = make_float4(a.x + b.x, a.y + b.y, a.z + b.z, a.w + b.w);
  ((float4*)(X + (size_t)t * D))[i] = v;
  ushort4 o = {f2b(v.x), f2b(v.y), f2b(v.z), f2b(v.w)};
  *(ushort4*)&Xb[(size_t)t * D + i * 4] = o;
}

// ---------------------------------------------------------------- add + LN
__global__ __launch_bounds__(256) void add_ln_kernel(
    const float* __restrict__ X, const float* __restrict__ Y,
    const float* __restrict__ g, const float* __restrict__ bta,
    float* __restrict__ Out, u16* __restrict__ Outb) {
  __shared__ float red[4];
  int t = blockIdx.x, i = threadIdx.x;
  const float4* xr = (const float4*)(X + (size_t)t * D);
  const float4* yr = (const float4*)(Y + (size_t)t * D);
  float4 a = xr[i], b = yr[i];
  float4 v = make_float4(a.x + b.x, a.y + b.y, a.z + b.z, a.w + b.w);
  float sum = v.x + v.y + v.z + v.w;
  sum = block_reduce_sum_256(sum, red);
  float mean = sum * (1.0f / D);
  float dx = v.x - mean, dy = v.y - mean, dz = v.z - mean, dw = v.w - mean;
  float sq = dx * dx + dy * dy + dz * dz + dw * dw;
  sq = block_reduce_sum_256(sq, red);
  float rstd = rsqrtf(sq * (1.0f / D) + 1e-5f);
  float4 gg = ((const float4*)g)[i];
  float4 bb = ((const float4*)bta)[i];
  float4 o = make_float4(dx * rstd * gg.x + bb.x, dy * rstd * gg.y + bb.y,
                         dz * rstd * gg.z + bb.z, dw * rstd * gg.w + bb.w);
  ((float4*)(Out + (size_t)t * D))[i] = o;
  ushort4 ob = {f2b(o.x), f2b(o.y), f2b(o.z), f2b(o.w)};
  *(ushort4*)&Outb[(size_t)t * D + i * 4] = ob;
}

// ---------------------------------------------------------------- transpose+cast
// W [K,N] fp32 -> WT [N,K] bf16.  Grid (N/32, K/32), 256 threads.
__global__ __launch_bounds__(256) void transpose_cast_kernel(
    const float* __restrict__ W, u16* __restrict__ WT, int K, int N) {
  __shared__ float t[32][33];
  int r = threadIdx.x >> 3, c4 = (threadIdx.x & 7) * 4;
  *(float4*)&t[r][c4] =
      *(const float4*)&W[(size_t)(blockIdx.y * 32 + r) * N + blockIdx.x * 32 + c4];
  __syncthreads();
  int n = blockIdx.x * 32 + r;
  int k = blockIdx.y * 32 + c4;
  ushort4 o = {f2b(t[c4 + 0][r]), f2b(t[c4 + 1][r]),
               f2b(t[c4 + 2][r]), f2b(t[c4 + 3][r])};
  *(ushort4*)&WT[(size_t)n * K + k] = o;
}

// ---------------------------------------------------------------- MFMA GEMM
// C[M,N] = A[M,K](bf16) @ BT[N,K](bf16)^T + bias.
// MODE: 0 = f32 out [r*N+c]; 1 = bf16 out; 2 = bf16+GeLU; 3 = bf16 transposed
// out Vt[c*MTOK + r] (V^T for attention PV).
template <int MODE>
__global__ __launch_bounds__(256) void gemm_mfma(
    const u16* __restrict__ A, const u16* __restrict__ BT,
    const float* __restrict__ bias, void* __restrict__ Cout,
    int M, int N, int K) {
  __shared__ u16 As[128][32];   // 8 KB
  __shared__ u16 Bs[128][32];   // 8 KB
  int tid = threadIdx.x;
  int row0 = blockIdx.y * 128, col0 = blockIdx.x * 128;
  int wid = tid >> 6, lane = tid & 63;
  int wr = (wid >> 1) * 64, wc = (wid & 1) * 64;
  int fr = lane & 15, fq = lane >> 4;

  f32x4 acc[4][4];
  #pragma unroll
  for (int m = 0; m < 4; m++)
    #pragma unroll
    for (int n = 0; n < 4; n++) acc[m][n] = (f32x4)(0.0f);

  for (int kt = 0; kt < K; kt += 32) {
    #pragma unroll
    for (int i = 0; i < 2; i++) {
      int f = i * 256 + tid;
      int r = f >> 2, ks = (f & 3) * 8;
      GLD16(A + (size_t)(row0 + r) * K + kt + ks, &As[r][ks]);
    }
    #pragma unroll
    for (int i = 0; i < 2; i++) {
      int f = i * 256 + tid;
      int r = f >> 2, ks = (f & 3) * 8;
      GLD16(BT + (size_t)(col0 + r) * K + kt + ks, &Bs[r][ks]);
    }
    __syncthreads();
    i32x4 av[4], bv[4];
    #pragma unroll
    for (int m = 0; m < 4; m++)
      av[m] = *(const i32x4*)&As[wr + m * 16 + fr][fq * 8];
    #pragma unroll
    for (int n = 0; n < 4; n++)
      bv[n] = *(const i32x4*)&Bs[wc + n * 16 + fr][fq * 8];
    #pragma unroll
    for (int m = 0; m < 4; m++)
      #pragma unroll
      for (int n = 0; n < 4; n++) mfma16(acc[m][n], av[m], bv[n]);
    __syncthreads();
  }

  // D layout: row = row0+wr+m*16+fq*4+j, col = col0+wc+n*16+fr
  float* Cf = (float*)Cout;
  u16*   Cb = (u16*)Cout;
  #pragma unroll
  for (int n = 0; n < 4; n++) {
    int c = col0 + wc + n * 16 + fr;
    float bvl = bias[c];
    #pragma unroll
    for (int m = 0; m < 4; m++) {
      int r0 = row0 + wr + m * 16 + fq * 4;
      if (MODE == 3) {
        ushort4 o = {f2b(acc[m][n][0] + bvl), f2b(acc[m][n][1] + bvl),
                     f2b(acc[m][n][2] + bvl), f2b(acc[m][n][3] + bvl)};
        *(ushort4*)&Cb[(size_t)c * MTOK + r0] = o;
      } else {
        #pragma unroll
        for (int j = 0; j < 4; j++) {
          float v = acc[m][n][j] + bvl;
          if (MODE == 2) v = gelu_f(v);
          if (MODE == 0) Cf[(size_t)(r0 + j) * N + c] = v;
          else           Cb[(size_t)(r0 + j) * N + c] = f2b(v);
        }
      }
    }
  }
}

// ---------------------------------------------------------------- MFMA attention
// Flash-style, 16x16x32 bf16 MFMA. Block: 256 thr = 4 waves; QBLK=128
// (32 q-rows/wave), KVBLK=64. K tile natural [kk][d]; V pre-transposed
// globally (Vt[c][token]) so PV's B-operand is row-major like the GEMM.
// K/Vt LDS tiles XOR-swizzled (slot ^= row&7; pre-swizzled global src,
// swizzled read — both-sides involution). P relayout via padded LDS (72).
__global__ __launch_bounds__(256) void attn_mfma(
    const u16* __restrict__ Q, const u16* __restrict__ K,
    const u16* __restrict__ Vt, const int* __restrict__ amask,
    u16* __restrict__ CTX) {
  __shared__ u16 Ks[64 * 64];        // 8 KB, swizzled slots
  __shared__ u16 Vts[64 * 64];       // 8 KB, swizzled slots
  __shared__ float maskadd[64];
  __shared__ u16 Ps[4][32 * 72];     // per-wave P, stride 72 (pad)

  int tid = threadIdx.x;
  int wave = tid >> 6, lane = tid & 63;
  int fr = lane & 15, fq = lane >> 4;
  int bh = blockIdx.y, b = bh >> 4, h = bh & 15;
  int q0 = blockIdx.x * 128 + wave * 32;

  // Q fragments (A-operand): lane holds Q[q0+qf*16+fr][d = dblk*32+fq*8 ..+7]
  i32x4 qa[2][2];
  #pragma unroll
  for (int qf = 0; qf < 2; qf++)
    #pragma unroll
    for (int dblk = 0; dblk < 2; dblk++)
      qa[qf][dblk] = *(const i32x4*)&Q[(size_t)(b * S + q0 + qf * 16 + fr) * D +
                                       h * HD + dblk * 32 + fq * 8];

  f32x4 acc_o[2][4];
  float m_run[2][4], l_run[2][4];
  #pragma unroll
  for (int qf = 0; qf < 2; qf++)
    #pragma unroll
    for (int j = 0; j < 4; j++) {
      m_run[qf][j] = -1e30f;
      l_run[qf][j] = 0.f;
      #pragma unroll
      for (int df = 0; df < 4; df++) acc_o[qf][df][j] = 0.f;
    }

  for (int k0 = 0; k0 < S; k0 += 64) {
    // ---- stage K tile [kk][d] and Vt tile [d][kk], pre-swizzled source
    #pragma unroll
    for (int i = 0; i < 2; i++) {
      int fi = i * 256 + tid;
      int r = fi >> 3, sl = fi & 7;
      int src = (sl ^ (r & 7)) * 8;
      GLD16(K + (size_t)(b * S + k0 + r) * D + h * HD + src, &Ks[fi * 8]);
    }
    #pragma unroll
    for (int i = 0; i < 2; i++) {
      int fi = i * 256 + tid;
      int r = fi >> 3, sl = fi & 7;
      int src = (sl ^ (r & 7)) * 8;
      GLD16(Vt + (size_t)(h * HD + r) * MTOK + b * S + k0 + src, &Vts[fi * 8]);
    }
    if (tid < 64) maskadd[tid] = amask[b * S + k0 + tid] ? 0.f : -1e9f;
    __syncthreads();

    float mk[4];
    #pragma unroll
    for (int kkf = 0; kkf < 4; kkf++) mk[kkf] = maskadd[kkf * 16 + fr];

    // ---- QK^T: S[q][kk], 16 MFMA
    f32x4 sc[2][4];
    #pragma unroll
    for (int qf = 0; qf < 2; qf++)
      #pragma unroll
      for (int kkf = 0; kkf < 4; kkf++) sc[qf][kkf] = (f32x4)(0.0f);
    #pragma unroll
    for (int kkf = 0; kkf < 4; kkf++) {
      int row = kkf * 16 + fr;
      #pragma unroll
      for (int dblk = 0; dblk < 2; dblk++) {
        i32x4 kb = *(const i32x4*)&Ks[row * 64 + (((dblk * 4 + fq) ^ (row & 7)) * 8)];
        mfma16(sc[0][kkf], qa[0][dblk], kb);
        mfma16(sc[1][kkf], qa[1][dblk], kb);
      }
    }

    // ---- online softmax; lane owns rows q = q0+qf*16+fq*4+j, cols kkf*16+fr
    #pragma unroll
    for (int qf = 0; qf < 2; qf++) {
      #pragma unroll
      for (int j = 0; j < 4; j++) {
        float s0 = sc[qf][0][j] * 0.125f + mk[0];
        float s1 = sc[qf][1][j] * 0.125f + mk[1];
        float s2 = sc[qf][2][j] * 0.125f + mk[2];
        float s3 = sc[qf][3][j] * 0.125f + mk[3];
        float mx = fmaxf(fmaxf(s0, s1), fmaxf(s2, s3));
        #pragma unroll
        for (int off = 1; off < 16; off <<= 1)
          mx = fmaxf(mx, __shfl_xor(mx, off, 64));
        float mold = m_run[qf][j];
        float mnew = fmaxf(mold, mx);
        float sf = __expf(mold - mnew);
        float p0 = __expf(s0 - mnew), p1 = __expf(s1 - mnew);
        float p2 = __expf(s2 - mnew), p3 = __expf(s3 - mnew);
        float ps = p0 + p1 + p2 + p3;
        #pragma unroll
        for (int off = 1; off < 16; off <<= 1)
          ps += __shfl_xor(ps, off, 64);
        l_run[qf][j] = l_run[qf][j] * sf + ps;
        m_run[qf][j] = mnew;
        #pragma unroll
        for (int df = 0; df < 4; df++) acc_o[qf][df][j] *= sf;
        int prow = (qf * 16 + fq * 4 + j) * 72;
        Ps[wave][prow +  0 + fr] = f2b(p0);
        Ps[wave][prow + 16 + fr] = f2b(p1);
        Ps[wave][prow + 32 + fr] = f2b(p2);
        Ps[wave][prow + 48 + fr] = f2b(p3);
      }
    }

    // ---- PV: O[q][d] += P @ V^T-tile, 16 MFMA (wave-local Ps: no barrier,
    // compiler orders ds_write -> ds_read via lgkmcnt)
    #pragma unroll
    for (int kkblk = 0; kkblk < 2; kkblk++) {
      i32x4 pa0 = *(const i32x4*)&Ps[wave][(fr) * 72 + kkblk * 32 + fq * 8];
      i32x4 pa1 = *(const i32x4*)&Ps[wave][(16 + fr) * 72 + kkblk * 32 + fq * 8];
      #pragma unroll
      for (int df = 0; df < 4; df++) {
        int row = df * 16 + fr;
        i32x4 vb = *(const i32x4*)&Vts[row * 64 + (((kkblk * 4 + fq) ^ (row & 7)) * 8)];
        mfma16(acc_o[0][df], pa0, vb);
        mfma16(acc_o[1][df], pa1, vb);
      }
    }
    __syncthreads();
  }

  // ---- epilogue: O[q = q0+qf*16+fq*4+j][d = df*16+fr]
  #pragma unroll
  for (int qf = 0; qf < 2; qf++) {
    #pragma unroll
    for (int j = 0; j < 4; j++) {
      float linv = 1.0f / l_run[qf][j];
      size_t base = (size_t)(b * S + q0 + qf * 16 + fq * 4 + j) * D + h * HD;
      #pragma unroll
      for (int df = 0; df < 4; df++)
        CTX[base + df * 16 + fr] = f2b(acc_o[qf][df][j] * linv);
    }
  }
}

// ---------------------------------------------------------------- classifier
__global__ __launch_bounds__(256) void classifier_kernel(
    const float* __restrict__ X, const float* __restrict__ g,
    const float* __restrict__ bta, const float* __restrict__ Wc,
    const float* __restrict__ bc, float* __restrict__ out) {
  __shared__ float red[4];
  __shared__ float xn[D];
  int b = blockIdx.x, i = threadIdx.x;
  const float4* xr = (const float4*)(X + (size_t)b * S * D);
  float4 v = xr[i];
  float sum = v.x + v.y + v.z + v.w;
  sum = block_reduce_sum_256(sum, red);
  float mean = sum * (1.0f / D);
  float dx = v.x - mean, dy = v.y - mean, dz = v.z - mean, dw = v.w - mean;
  float sq = dx * dx + dy * dy + dz * dz + dw * dw;
  sq = block_reduce_sum_256(sq, red);
  float rstd = rsqrtf(sq * (1.0f / D) + 1e-5f);
  float4 gg = ((const float4*)g)[i];
  float4 bb = ((const float4*)bta)[i];
  float4 o = make_float4(dx * rstd * gg.x + bb.x, dy * rstd * gg.y + bb.y,
                         dz * rstd * gg.z + bb.z, dw * rstd * gg.w + bb.w);
  *(float4*)&xn[i * 4] = o;
  __syncthreads();
  for (int c = 0; c < C; c++) {
    float p = 0.f;
    for (int d = i; d < D; d += 256) p += xn[d] * Wc[(size_t)d * C + c];
    p = block_reduce_sum_256(p, red);
    if (i == 0) out[b * C + c] = p + bc[c];
  }
}

// ---------------------------------------------------------------- launch
extern "C" void kernel_launch(void* const* d_in, const int* in_sizes, int n_in,
                              void* d_out, int out_size, void* d_ws,
                              size_t ws_size, hipStream_t stream) {
  const int*   ids   = (const int*)d_in[0];
  const int*   amask = (const int*)d_in[1];
  const float* emb   = (const float*)d_in[2];
  const float* pos   = (const float*)d_in[3];
  const float* Wq    = (const float*)d_in[4];
  const float* bq    = (const float*)d_in[5];
  const float* Wk    = (const float*)d_in[6];
  const float* bk    = (const float*)d_in[7];
  const float* Wv    = (const float*)d_in[8];
  const float* bv    = (const float*)d_in[9];
  const float* Wo    = (const float*)d_in[10];
  const float* bo    = (const float*)d_in[11];
  const float* ln1g  = (const float*)d_in[12];
  const float* ln1b  = (const float*)d_in[13];
  const float* ln2g  = (const float*)d_in[14];
  const float* ln2b  = (const float*)d_in[15];
  const float* W1    = (const float*)d_in[16];
  const float* b1    = (const float*)d_in[17];
  const float* W2    = (const float*)d_in[18];
  const float* b2    = (const float*)d_in[19];
  const float* cg    = (const float*)d_in[20];
  const float* cb    = (const float*)d_in[21];
  const float* Wc    = (const float*)d_in[22];
  const float* bc    = (const float*)d_in[23];
  float* logits = (float*)d_out;

  // Workspace layout (bytes), total 168 MB:
  //   [0,32M)    X    fp32 residual
  //   [32,64M)   Y    fp32 temp
  //   [64,80M)   Xb   bf16 residual
  //   [80,96M)   Qb | [96,112M) Kbuf | [112,128M) Vt (V^T: [D][MTOK])
  //   [128,144M) CTXb ; Hh aliases [80,144M) (dead by FF)
  //   [144,168M) per-layer transposed bf16 weights
  const size_t MB = 1u << 20;
  char* w = (char*)d_ws;
  float* X   = (float*)(w + 0 * MB);
  float* Y   = (float*)(w + 32 * MB);
  u16* Xb    = (u16*)(w + 64 * MB);
  u16* Qb    = (u16*)(w + 80 * MB);
  u16* Kbuf  = (u16*)(w + 96 * MB);
  u16* Vt    = (u16*)(w + 112 * MB);
  u16* CTXb  = (u16*)(w + 128 * MB);
  u16* Hh    = (u16*)(w + 80 * MB);
  u16* WTq   = (u16*)(w + 144 * MB);
  u16* WTk   = (u16*)(w + 146 * MB);
  u16* WTv   = (u16*)(w + 148 * MB);
  u16* WTo   = (u16*)(w + 150 * MB);
  u16* WT1   = (u16*)(w + 152 * MB);
  u16* WT2   = (u16*)(w + 160 * MB);

  embed_kernel<<<MTOK, 256, 0, stream>>>(ids, emb, pos, X, Xb);

  dim3 tDD(D / 32, D / 32);
  dim3 tFD(F / 32, D / 32);
  dim3 tDF(D / 32, F / 32);
  dim3 gD(D / 128, MTOK / 128);
  dim3 gF(F / 128, MTOK / 128);

  for (int l = 0; l < NL; l++) {
    transpose_cast_kernel<<<tDD, 256, 0, stream>>>(Wq + (size_t)l * D * D, WTq, D, D);
    transpose_cast_kernel<<<tDD, 256, 0, stream>>>(Wk + (size_t)l * D * D, WTk, D, D);
    transpose_cast_kernel<<<tDD, 256, 0, stream>>>(Wv + (size_t)l * D * D, WTv, D, D);
    transpose_cast_kernel<<<tDD, 256, 0, stream>>>(Wo + (size_t)l * D * D, WTo, D, D);
    transpose_cast_kernel<<<tFD, 256, 0, stream>>>(W1 + (size_t)l * D * F, WT1, D, F);
    transpose_cast_kernel<<<tDF, 256, 0, stream>>>(W2 + (size_t)l * F * D, WT2, F, D);

    gemm_mfma<1><<<gD, 256, 0, stream>>>(Xb, WTq, bq + l * D, Qb,   MTOK, D, D);
    gemm_mfma<1><<<gD, 256, 0, stream>>>(Xb, WTk, bk + l * D, Kbuf, MTOK, D, D);
    gemm_mfma<3><<<gD, 256, 0, stream>>>(Xb, WTv, bv + l * D, Vt,   MTOK, D, D);

    attn_mfma<<<dim3(S / 128, B * H), 256, 0, stream>>>(
        Qb, Kbuf, Vt, amask, CTXb);

    gemm_mfma<0><<<gD, 256, 0, stream>>>(CTXb, WTo, bo + l * D, Y, MTOK, D, D);
    add_ln_kernel<<<MTOK, 256, 0, stream>>>(X, Y, ln1g + l * D, ln1b + l * D, X, Xb);

    gemm_mfma<2><<<gF, 256, 0, stream>>>(Xb, WT1, b1 + l * F, Hh, MTOK, F, D);
    gemm_mfma<0><<<gD, 256, 0, stream>>>(Hh, WT2, b2 + l * D, Y, MTOK, D, F);
    add_ln_kernel<<<MTOK, 256, 0, stream>>>(X, Y, ln2g + l * D, ln2b + l * D, X, Xb);
  }
  classifier_kernel<<<B, 256, 0, stream>>>(X, cg, cb, Wc, bc, logits);
}

// Round 6
// 1638.372 us; speedup vs baseline: 7.1332x; 1.0504x over previous
//
#include <hip/hip_runtime.h>
#include <math.h>

// Problem constants
constexpr int S  = 1024;
constexpr int D  = 1024;
constexpr int H  = 16;
constexpr int F  = 4096;
constexpr int NL = 3;
constexpr int C  = 5;
constexpr int HD = 64;
constexpr int B  = 8;
constexpr int MTOK = B * S;          // 8192 token rows

typedef unsigned short u16;
typedef __attribute__((ext_vector_type(4))) float f32x4;
typedef __attribute__((ext_vector_type(4))) int   i32x4;

// ---- bf16 <-> f32 helpers (RNE) --------------------------------------------
__device__ inline u16 f2b(float x) {
  unsigned u = __float_as_uint(x);
  unsigned r = (u + 0x7fffu + ((u >> 16) & 1u)) >> 16;
  return (u16)r;
}
__device__ inline float b2f(u16 b) {
  return __uint_as_float(((unsigned)b) << 16);
}

// ---- async global->LDS, 16B per lane ---------------------------------------
#define GLD16(gptr, lptr)                                                  \
  __builtin_amdgcn_global_load_lds(                                        \
      (const __attribute__((address_space(1))) void*)(gptr),               \
      (__attribute__((address_space(3))) void*)(lptr), 16, 0, 0)

// ---- MFMA -------------------------------------------------------------------
__device__ inline void mfma16(f32x4& acc, i32x4 a, i32x4 b) {
  asm("v_mfma_f32_16x16x32_bf16 %0, %1, %2, %0" : "+v"(acc) : "v"(a), "v"(b));
}

// ---------------------------------------------------------------- reductions
__device__ inline float block_reduce_sum_256(float v, float* red) {
  #pragma unroll
  for (int off = 32; off > 0; off >>= 1) v += __shfl_down(v, off, 64);
  int lane = threadIdx.x & 63, wid = threadIdx.x >> 6;
  if (lane == 0) red[wid] = v;
  __syncthreads();
  float t = red[0] + red[1] + red[2] + red[3];
  __syncthreads();
  return t;
}

__device__ inline float gelu_f(float x) {
  return 0.5f * x * (1.0f + erff(x * 0.70710678118654752f));
}

// ---------------------------------------------------------------- embedding
__global__ __launch_bounds__(256) void embed_kernel(
    const int* __restrict__ ids, const float* __restrict__ emb,
    const float* __restrict__ pos, float* __restrict__ X,
    u16* __restrict__ Xb) {
  int t = blockIdx.x;
  int s = t & (S - 1);
  size_t id = (size_t)ids[t];
  const float4* e = (const float4*)(emb + id * (size_t)D);
  const float4* p = (const float4*)(pos + (size_t)s * D);
  int i = threadIdx.x;
  float4 a = e[i], b = p[i];
  float4 v = make_float4(a.x + b.x, a.y + b.y, a.z + b.z, a.w + b.w);
  ((float4*)(X + (size_t)t * D))[i] = v;
  ushort4 o = {f2b(v.x), f2b(v.y), f2b(v.z), f2b(v.w)};
  *(ushort4*)&Xb[(size_t)t * D + i * 4] = o;
}

// ---------------------------------------------------------------- add + LN
__global__ __launch_bounds__(256) void add_ln_kernel(
    const float* __restrict__ X, const float* __restrict__ Y,
    const float* __restrict__ g, const float* __restrict__ bta,
    float* __restrict__ Out, u16* __restrict__ Outb) {
  __shared__ float red[4];
  int t = blockIdx.x, i = threadIdx.x;
  const float4* xr = (const float4*)(X + (size_t)t * D);
  const float4* yr = (const float4*)(Y + (size_t)t * D);
  float4 a = xr[i], b = yr[i];
  float4 v = make_float4(a.x + b.x, a.y + b.y, a.z + b.z, a.w + b.w);
  float sum = v.x + v.y + v.z + v.w;
  sum = block_reduce_sum_256(sum, red);
  float mean = sum * (1.0f / D);
  float dx = v.x - mean, dy = v.y - mean, dz = v.z - mean, dw = v.w - mean;
  float sq = dx * dx + dy * dy + dz * dz + dw * dw;
  sq = block_reduce_sum_256(sq, red);
  float rstd = rsqrtf(sq * (1.0f / D) + 1e-5f);
  float4 gg = ((const float4*)g)[i];
  float4 bb = ((const float4*)bta)[i];
  float4 o = make_float4(dx * rstd * gg.x + bb.x, dy * rstd * gg.y + bb.y,
                         dz * rstd * gg.z + bb.z, dw * rstd * gg.w + bb.w);
  ((float4*)(Out + (size_t)t * D))[i] = o;
  ushort4 ob = {f2b(o.x), f2b(o.y), f2b(o.z), f2b(o.w)};
  *(ushort4*)&Outb[(size_t)t * D + i * 4] = ob;
}

// ---------------------------------------------------------------- transpose+cast
// W [K,N] fp32 -> WT [N,K] bf16.  Grid (N/32, K/32), 256 threads.
__global__ __launch_bounds__(256) void transpose_cast_kernel(
    const float* __restrict__ W, u16* __restrict__ WT, int K, int N) {
  __shared__ float t[32][33];
  int r = threadIdx.x >> 3, c4 = (threadIdx.x & 7) * 4;
  *(float4*)&t[r][c4] =
      *(const float4*)&W[(size_t)(blockIdx.y * 32 + r) * N + blockIdx.x * 32 + c4];
  __syncthreads();
  int n = blockIdx.x * 32 + r;
  int k = blockIdx.y * 32 + c4;
  ushort4 o = {f2b(t[c4 + 0][r]), f2b(t[c4 + 1][r]),
               f2b(t[c4 + 2][r]), f2b(t[c4 + 3][r])};
  *(ushort4*)&WT[(size_t)n * K + k] = o;
}

// ---------------------------------------------------------------- bias pack
// Bqkv[l][0:1024)=bq[l], [1024:2048)=bk[l], [2048:3072)=bv[l].
__global__ __launch_bounds__(256) void pack_bias_kernel(
    const float* __restrict__ bq, const float* __restrict__ bk,
    const float* __restrict__ bv, float* __restrict__ Bqkv) {
  int l = blockIdx.x;
  for (int i = threadIdx.x; i < 3 * D; i += 256) {
    int seg = i >> 10, j = i & 1023;
    const float* src = seg == 0 ? bq : (seg == 1 ? bk : bv);
    Bqkv[l * 3 * D + i] = src[l * D + j];
  }
}

// ---------------------------------------------------------------- MFMA GEMM
// C[M,N] = A[M,K](bf16) @ BT[N,K](bf16)^T + bias.
// MODE: 0 = f32 out [r*N+c]; 1 = bf16 out; 2 = bf16+GeLU;
//       3 = bf16 transposed out Vt[c*MTOK + r];
//       4 = fused QKV routing (col segment 0->outQ bf16, 1->outK bf16,
//           2->outVt transposed), row stride D.
// K-loop: double-buffered LDS, prefetch-next-before-compute (T3-min 2-phase).
template <int MODE>
__global__ __launch_bounds__(256) void gemm_mfma(
    const u16* __restrict__ A, const u16* __restrict__ BT,
    const float* __restrict__ bias, void* __restrict__ Cout,
    int M, int N, int K,
    u16* __restrict__ outK, u16* __restrict__ outVt) {
  __shared__ u16 As[2][128][32];   // 16 KB
  __shared__ u16 Bs[2][128][32];   // 16 KB
  int tid = threadIdx.x;
  int row0 = blockIdx.y * 128, col0 = blockIdx.x * 128;
  int wid = tid >> 6, lane = tid & 63;
  int wr = (wid >> 1) * 64, wc = (wid & 1) * 64;
  int fr = lane & 15, fq = lane >> 4;

  f32x4 acc[4][4];
  #pragma unroll
  for (int m = 0; m < 4; m++)
    #pragma unroll
    for (int n = 0; n < 4; n++) acc[m][n] = (f32x4)(0.0f);

  int sr = tid >> 2, sks = (tid & 3) * 8;          // staging coords
  const u16* Abase = A + (size_t)(row0 + sr) * K + sks;
  const u16* Bbase = BT + (size_t)(col0 + sr) * K + sks;

  auto stage = [&](int bufi, int kt) {
    GLD16(Abase + kt, &As[bufi][sr][sks]);
    GLD16(Abase + (size_t)64 * K + kt, &As[bufi][64 + sr][sks]);
    GLD16(Bbase + kt, &Bs[bufi][sr][sks]);
    GLD16(Bbase + (size_t)64 * K + kt, &Bs[bufi][64 + sr][sks]);
  };
  auto compute = [&](int bufi) {
    i32x4 av[4], bv[4];
    #pragma unroll
    for (int m = 0; m < 4; m++)
      av[m] = *(const i32x4*)&As[bufi][wr + m * 16 + fr][fq * 8];
    #pragma unroll
    for (int n = 0; n < 4; n++)
      bv[n] = *(const i32x4*)&Bs[bufi][wc + n * 16 + fr][fq * 8];
    #pragma unroll
    for (int m = 0; m < 4; m++)
      #pragma unroll
      for (int n = 0; n < 4; n++) mfma16(acc[m][n], av[m], bv[n]);
  };

  stage(0, 0);
  __syncthreads();                       // drain prefetch of tile 0
  int cur = 0;
  for (int kt = 32; kt < K; kt += 32) {
    stage(cur ^ 1, kt);                  // async prefetch next tile
    compute(cur);                        // overlaps with loads in flight
    __syncthreads();                     // vmcnt(0)+lgkmcnt(0)+barrier
    cur ^= 1;
  }
  compute(cur);

  // D layout: row = row0+wr+m*16+fq*4+j, col = col0+wc+n*16+fr
  float* Cf = (float*)Cout;
  u16*   Cb = (u16*)Cout;
  #pragma unroll
  for (int n = 0; n < 4; n++) {
    int c = col0 + wc + n * 16 + fr;
    float bvl = bias[c];
    #pragma unroll
    for (int m = 0; m < 4; m++) {
      int r0 = row0 + wr + m * 16 + fq * 4;
      if (MODE == 3) {
        ushort4 o = {f2b(acc[m][n][0] + bvl), f2b(acc[m][n][1] + bvl),
                     f2b(acc[m][n][2] + bvl), f2b(acc[m][n][3] + bvl)};
        *(ushort4*)&Cb[(size_t)c * MTOK + r0] = o;
      } else if (MODE == 4) {
        int seg = c >> 10, cl = c & 1023;
        if (seg == 2) {
          ushort4 o = {f2b(acc[m][n][0] + bvl), f2b(acc[m][n][1] + bvl),
                       f2b(acc[m][n][2] + bvl), f2b(acc[m][n][3] + bvl)};
          *(ushort4*)&outVt[(size_t)cl * MTOK + r0] = o;
        } else {
          u16* dst = seg == 0 ? Cb : outK;
          #pragma unroll
          for (int j = 0; j < 4; j++)
            dst[(size_t)(r0 + j) * D + cl] = f2b(acc[m][n][j] + bvl);
        }
      } else {
        #pragma unroll
        for (int j = 0; j < 4; j++) {
          float v = acc[m][n][j] + bvl;
          if (MODE == 2) v = gelu_f(v);
          if (MODE == 0) Cf[(size_t)(r0 + j) * N + c] = v;
          else           Cb[(size_t)(r0 + j) * N + c] = f2b(v);
        }
      }
    }
  }
}

// ---------------------------------------------------------------- MFMA attention
// Flash-style, 16x16x32 bf16 MFMA. Block: 256 thr = 4 waves; QBLK=128
// (32 q-rows/wave), KVBLK=64. K tile natural [kk][d]; V pre-transposed
// globally (Vt[c][token]) so PV's B-operand is row-major like the GEMM.
// K/Vt LDS tiles XOR-swizzled (slot ^= row&7; pre-swizzled global src,
// swizzled read — both-sides involution). P relayout via padded LDS (72).
__global__ __launch_bounds__(256) void attn_mfma(
    const u16* __restrict__ Q, const u16* __restrict__ K,
    const u16* __restrict__ Vt, const int* __restrict__ amask,
    u16* __restrict__ CTX) {
  __shared__ u16 Ks[64 * 64];        // 8 KB, swizzled slots
  __shared__ u16 Vts[64 * 64];       // 8 KB, swizzled slots
  __shared__ float maskadd[64];
  __shared__ u16 Ps[4][32 * 72];     // per-wave P, stride 72 (pad)

  int tid = threadIdx.x;
  int wave = tid >> 6, lane = tid & 63;
  int fr = lane & 15, fq = lane >> 4;
  int bh = blockIdx.y, b = bh >> 4, h = bh & 15;
  int q0 = blockIdx.x * 128 + wave * 32;

  // Q fragments (A-operand): lane holds Q[q0+qf*16+fr][d = dblk*32+fq*8 ..+7]
  i32x4 qa[2][2];
  #pragma unroll
  for (int qf = 0; qf < 2; qf++)
    #pragma unroll
    for (int dblk = 0; dblk < 2; dblk++)
      qa[qf][dblk] = *(const i32x4*)&Q[(size_t)(b * S + q0 + qf * 16 + fr) * D +
                                       h * HD + dblk * 32 + fq * 8];

  f32x4 acc_o[2][4];
  float m_run[2][4], l_run[2][4];
  #pragma unroll
  for (int qf = 0; qf < 2; qf++)
    #pragma unroll
    for (int j = 0; j < 4; j++) {
      m_run[qf][j] = -1e30f;
      l_run[qf][j] = 0.f;
      #pragma unroll
      for (int df = 0; df < 4; df++) acc_o[qf][df][j] = 0.f;
    }

  for (int k0 = 0; k0 < S; k0 += 64) {
    // ---- stage K tile [kk][d] and Vt tile [d][kk], pre-swizzled source
    #pragma unroll
    for (int i = 0; i < 2; i++) {
      int fi = i * 256 + tid;
      int r = fi >> 3, sl = fi & 7;
      int src = (sl ^ (r & 7)) * 8;
      GLD16(K + (size_t)(b * S + k0 + r) * D + h * HD + src, &Ks[fi * 8]);
    }
    #pragma unroll
    for (int i = 0; i < 2; i++) {
      int fi = i * 256 + tid;
      int r = fi >> 3, sl = fi & 7;
      int src = (sl ^ (r & 7)) * 8;
      GLD16(Vt + (size_t)(h * HD + r) * MTOK + b * S + k0 + src, &Vts[fi * 8]);
    }
    if (tid < 64) maskadd[tid] = amask[b * S + k0 + tid] ? 0.f : -1e9f;
    __syncthreads();

    float mk[4];
    #pragma unroll
    for (int kkf = 0; kkf < 4; kkf++) mk[kkf] = maskadd[kkf * 16 + fr];

    // ---- QK^T: S[q][kk], 16 MFMA
    f32x4 sc[2][4];
    #pragma unroll
    for (int qf = 0; qf < 2; qf++)
      #pragma unroll
      for (int kkf = 0; kkf < 4; kkf++) sc[qf][kkf] = (f32x4)(0.0f);
    #pragma unroll
    for (int kkf = 0; kkf < 4; kkf++) {
      int row = kkf * 16 + fr;
      #pragma unroll
      for (int dblk = 0; dblk < 2; dblk++) {
        i32x4 kb = *(const i32x4*)&Ks[row * 64 + (((dblk * 4 + fq) ^ (row & 7)) * 8)];
        mfma16(sc[0][kkf], qa[0][dblk], kb);
        mfma16(sc[1][kkf], qa[1][dblk], kb);
      }
    }

    // ---- online softmax; lane owns rows q = q0+qf*16+fq*4+j, cols kkf*16+fr
    #pragma unroll
    for (int qf = 0; qf < 2; qf++) {
      #pragma unroll
      for (int j = 0; j < 4; j++) {
        float s0 = sc[qf][0][j] * 0.125f + mk[0];
        float s1 = sc[qf][1][j] * 0.125f + mk[1];
        float s2 = sc[qf][2][j] * 0.125f + mk[2];
        float s3 = sc[qf][3][j] * 0.125f + mk[3];
        float mx = fmaxf(fmaxf(s0, s1), fmaxf(s2, s3));
        #pragma unroll
        for (int off = 1; off < 16; off <<= 1)
          mx = fmaxf(mx, __shfl_xor(mx, off, 64));
        float mold = m_run[qf][j];
        float mnew = fmaxf(mold, mx);
        float sf = __expf(mold - mnew);
        float p0 = __expf(s0 - mnew), p1 = __expf(s1 - mnew);
        float p2 = __expf(s2 - mnew), p3 = __expf(s3 - mnew);
        float ps = p0 + p1 + p2 + p3;
        #pragma unroll
        for (int off = 1; off < 16; off <<= 1)
          ps += __shfl_xor(ps, off, 64);
        l_run[qf][j] = l_run[qf][j] * sf + ps;
        m_run[qf][j] = mnew;
        #pragma unroll
        for (int df = 0; df < 4; df++) acc_o[qf][df][j] *= sf;
        int prow = (qf * 16 + fq * 4 + j) * 72;
        Ps[wave][prow +  0 + fr] = f2b(p0);
        Ps[wave][prow + 16 + fr] = f2b(p1);
        Ps[wave][prow + 32 + fr] = f2b(p2);
        Ps[wave][prow + 48 + fr] = f2b(p3);
      }
    }

    // ---- PV: O[q][d] += P @ V^T-tile, 16 MFMA (wave-local Ps: no barrier,
    // compiler orders ds_write -> ds_read via lgkmcnt)
    #pragma unroll
    for (int kkblk = 0; kkblk < 2; kkblk++) {
      i32x4 pa0 = *(const i32x4*)&Ps[wave][(fr) * 72 + kkblk * 32 + fq * 8];
      i32x4 pa1 = *(const i32x4*)&Ps[wave][(16 + fr) * 72 + kkblk * 32 + fq * 8];
      #pragma unroll
      for (int df = 0; df < 4; df++) {
        int row = df * 16 + fr;
        i32x4 vb = *(const i32x4*)&Vts[row * 64 + (((kkblk * 4 + fq) ^ (row & 7)) * 8)];
        mfma16(acc_o[0][df], pa0, vb);
        mfma16(acc_o[1][df], pa1, vb);
      }
    }
    __syncthreads();
  }

  // ---- epilogue: O[q = q0+qf*16+fq*4+j][d = df*16+fr]
  #pragma unroll
  for (int qf = 0; qf < 2; qf++) {
    #pragma unroll
    for (int j = 0; j < 4; j++) {
      float linv = 1.0f / l_run[qf][j];
      size_t base = (size_t)(b * S + q0 + qf * 16 + fq * 4 + j) * D + h * HD;
      #pragma unroll
      for (int df = 0; df < 4; df++)
        CTX[base + df * 16 + fr] = f2b(acc_o[qf][df][j] * linv);
    }
  }
}

// ---------------------------------------------------------------- classifier
__global__ __launch_bounds__(256) void classifier_kernel(
    const float* __restrict__ X, const float* __restrict__ g,
    const float* __restrict__ bta, const float* __restrict__ Wc,
    const float* __restrict__ bc, float* __restrict__ out) {
  __shared__ float red[4];
  __shared__ float xn[D];
  int b = blockIdx.x, i = threadIdx.x;
  const float4* xr = (const float4*)(X + (size_t)b * S * D);
  float4 v = xr[i];
  float sum = v.x + v.y + v.z + v.w;
  sum = block_reduce_sum_256(sum, red);
  float mean = sum * (1.0f / D);
  float dx = v.x - mean, dy = v.y - mean, dz = v.z - mean, dw = v.w - mean;
  float sq = dx * dx + dy * dy + dz * dz + dw * dw;
  sq = block_reduce_sum_256(sq, red);
  float rstd = rsqrtf(sq * (1.0f / D) + 1e-5f);
  float4 gg = ((const float4*)g)[i];
  float4 bb = ((const float4*)bta)[i];
  float4 o = make_float4(dx * rstd * gg.x + bb.x, dy * rstd * gg.y + bb.y,
                         dz * rstd * gg.z + bb.z, dw * rstd * gg.w + bb.w);
  *(float4*)&xn[i * 4] = o;
  __syncthreads();
  for (int c = 0; c < C; c++) {
    float p = 0.f;
    for (int d = i; d < D; d += 256) p += xn[d] * Wc[(size_t)d * C + c];
    p = block_reduce_sum_256(p, red);
    if (i == 0) out[b * C + c] = p + bc[c];
  }
}

// ---------------------------------------------------------------- launch
extern "C" void kernel_launch(void* const* d_in, const int* in_sizes, int n_in,
                              void* d_out, int out_size, void* d_ws,
                              size_t ws_size, hipStream_t stream) {
  const int*   ids   = (const int*)d_in[0];
  const int*   amask = (const int*)d_in[1];
  const float* emb   = (const float*)d_in[2];
  const float* pos   = (const float*)d_in[3];
  const float* Wq    = (const float*)d_in[4];
  const float* bq    = (const float*)d_in[5];
  const float* Wk    = (const float*)d_in[6];
  const float* bk    = (const float*)d_in[7];
  const float* Wv    = (const float*)d_in[8];
  const float* bv    = (const float*)d_in[9];
  const float* Wo    = (const float*)d_in[10];
  const float* bo    = (const float*)d_in[11];
  const float* ln1g  = (const float*)d_in[12];
  const float* ln1b  = (const float*)d_in[13];
  const float* ln2g  = (const float*)d_in[14];
  const float* ln2b  = (const float*)d_in[15];
  const float* W1    = (const float*)d_in[16];
  const float* b1    = (const float*)d_in[17];
  const float* W2    = (const float*)d_in[18];
  const float* b2    = (const float*)d_in[19];
  const float* cg    = (const float*)d_in[20];
  const float* cb    = (const float*)d_in[21];
  const float* Wc    = (const float*)d_in[22];
  const float* bc    = (const float*)d_in[23];
  float* logits = (float*)d_out;

  // Workspace layout (bytes), ~169 MB:
  //   [0,32M)    X    fp32 residual
  //   [32,64M)   Y    fp32 temp
  //   [64,80M)   Xb   bf16 residual
  //   [80,96M)   Qb | [96,112M) Kbuf | [112,128M) Vt ([D][MTOK])
  //   [128,144M) CTXb ; Hh aliases [80,144M) (dead by FF)
  //   [144,150M) WTqkv (contig [3072][1024] bf16) | [150,152M) WTo
  //   [152,160M) WT1 | [160,168M) WT2 | [168M..) Bqkv 3x3072 f32
  const size_t MB = 1u << 20;
  char* w = (char*)d_ws;
  float* X   = (float*)(w + 0 * MB);
  float* Y   = (float*)(w + 32 * MB);
  u16* Xb    = (u16*)(w + 64 * MB);
  u16* Qb    = (u16*)(w + 80 * MB);
  u16* Kbuf  = (u16*)(w + 96 * MB);
  u16* Vt    = (u16*)(w + 112 * MB);
  u16* CTXb  = (u16*)(w + 128 * MB);
  u16* Hh    = (u16*)(w + 80 * MB);
  u16* WTqkv = (u16*)(w + 144 * MB);            // rows 0..1023 Q, ..2047 K, ..3071 V
  u16* WTq   = WTqkv;
  u16* WTk   = WTqkv + (size_t)D * D;
  u16* WTv   = WTqkv + (size_t)2 * D * D;
  u16* WTo   = (u16*)(w + 150 * MB);
  u16* WT1   = (u16*)(w + 152 * MB);
  u16* WT2   = (u16*)(w + 160 * MB);
  float* Bqkv = (float*)(w + 168 * MB);

  embed_kernel<<<MTOK, 256, 0, stream>>>(ids, emb, pos, X, Xb);
  pack_bias_kernel<<<NL, 256, 0, stream>>>(bq, bk, bv, Bqkv);

  dim3 tDD(D / 32, D / 32);
  dim3 tFD(F / 32, D / 32);
  dim3 tDF(D / 32, F / 32);
  dim3 gD(D / 128, MTOK / 128);
  dim3 gQKV(3 * D / 128, MTOK / 128);
  dim3 gF(F / 128, MTOK / 128);

  for (int l = 0; l < NL; l++) {
    transpose_cast_kernel<<<tDD, 256, 0, stream>>>(Wq + (size_t)l * D * D, WTq, D, D);
    transpose_cast_kernel<<<tDD, 256, 0, stream>>>(Wk + (size_t)l * D * D, WTk, D, D);
    transpose_cast_kernel<<<tDD, 256, 0, stream>>>(Wv + (size_t)l * D * D, WTv, D, D);
    transpose_cast_kernel<<<tDD, 256, 0, stream>>>(Wo + (size_t)l * D * D, WTo, D, D);
    transpose_cast_kernel<<<tFD, 256, 0, stream>>>(W1 + (size_t)l * D * F, WT1, D, F);
    transpose_cast_kernel<<<tDF, 256, 0, stream>>>(W2 + (size_t)l * F * D, WT2, F, D);

    // Fused QKV: one GEMM vs WTqkv[3072][1024]; epilogue routes per segment.
    gemm_mfma<4><<<gQKV, 256, 0, stream>>>(
        Xb, WTqkv, Bqkv + l * 3 * D, Qb, MTOK, 3 * D, D, Kbuf, Vt);

    attn_mfma<<<dim3(S / 128, B * H), 256, 0, stream>>>(
        Qb, Kbuf, Vt, amask, CTXb);

    gemm_mfma<0><<<gD, 256, 0, stream>>>(CTXb, WTo, bo + l * D, Y, MTOK, D, D,
                                         nullptr, nullptr);
    add_ln_kernel<<<MTOK, 256, 0, stream>>>(X, Y, ln1g + l * D, ln1b + l * D, X, Xb);

    gemm_mfma<2><<<gF, 256, 0, stream>>>(Xb, WT1, b1 + l * F, Hh, MTOK, F, D,
                                         nullptr, nullptr);
    gemm_mfma<0><<<gD, 256, 0, stream>>>(Hh, WT2, b2 + l * D, Y, MTOK, D, F,
                                         nullptr, nullptr);
    add_ln_kernel<<<MTOK, 256, 0, stream>>>(X, Y, ln2g + l * D, ln2b + l * D, X, Xb);
  }
  classifier_kernel<<<B, 256, 0, stream>>>(X, cg, cb, Wc, bc, logits);
}